// Round 7
// baseline (235.196 us; speedup 1.0000x reference)
//
#include <hip/hip_runtime.h>
#include <math.h>

#define T_TOKENS 16384
#define D_DIM    2048
#define E_EXP    64
#define TOPK     8
#define NS       8              // split-K slices
#define NCH      (D_DIM / NS / 32)   // 8 k-chunks of 32 per slice

typedef __attribute__((ext_vector_type(8))) short bf16x8;
typedef __attribute__((ext_vector_type(4))) float f32x4;

__device__ __forceinline__ unsigned short bf16rne(float f) {
  unsigned u = __builtin_bit_cast(unsigned, f);
  unsigned r = u + 0x7fffu + ((u >> 16) & 1u);
  return (unsigned short)(r >> 16);
}
__device__ __forceinline__ float bf16f(unsigned short h) {
  return __builtin_bit_cast(float, (unsigned)h << 16);
}

// Split one float4-pair (8 floats) into hi/lo bf16x8 fragments.
__device__ __forceinline__ void split8(const float4 v0, const float4 v1,
                                       bf16x8& hi, bf16x8& lo) {
  const float xs[8] = {v0.x, v0.y, v0.z, v0.w, v1.x, v1.y, v1.z, v1.w};
  #pragma unroll
  for (int j = 0; j < 8; ++j) {
    unsigned short h = bf16rne(xs[j]);
    hi[j] = (short)h;
    lo[j] = (short)bf16rne(xs[j] - bf16f(h));
  }
}

// ---------------- Kernel 0: pre-convert gate_w to frag-ordered bf16 hi/lo ----
// entry id = ((c*4 + kq)*64 + e): c = k/32 chunk, kq = k-quad, e = expert.
// Entry = 8 bf16 (16 B) = g[e][c*32 + kq*8 .. +7]. Also zeroes counts region.
__global__ __launch_bounds__(256) void convert_g_kernel(
    const float* __restrict__ gw, unsigned short* __restrict__ ph,
    unsigned short* __restrict__ pl, float* __restrict__ counts_zero)
{
  const int id = blockIdx.x * 256 + threadIdx.x;   // 0..16383
  if (blockIdx.x == 0 && threadIdx.x < E_EXP) counts_zero[threadIdx.x] = 0.0f;

  const int e  = id & 63;
  const int kq = (id >> 6) & 3;
  const int c  = id >> 8;
  const float* gp = &gw[(size_t)e * D_DIM + c * 32 + kq * 8];
  float4 v0 = *(const float4*)&gp[0];
  float4 v1 = *(const float4*)&gp[4];
  bf16x8 hi, lo;
  split8(v0, v1, hi, lo);
  *(bf16x8*)&ph[(size_t)id * 8] = hi;
  *(bf16x8*)&pl[(size_t)id * 8] = lo;
}

// ---------------- Kernel 1: partial logits via split-bf16 MFMA ----------------
// grid (T/128, NS), 256 thr = 4 waves, no LDS/barriers. Wave: 32 tok x 64 exp.
// Register pipeline per 32-k chunk:
//   prefetch next chunk's x (4 x b128, HBM) -> convert current x -> per et:
//   load bh/bl (transient, L2-hot 256 B segments) + 8 MFMAs (hh,hl,lh,ll x 2 sub).
// Live VGPRs ~105 (acc 32, a-frags 16, x-next 16, B 8-16, addr ~16) -> no spill
// at the 128 cap from __launch_bounds__(256,4).
__global__ __launch_bounds__(256, 4) void moe_logits_kernel(
    const float* __restrict__ x, const unsigned short* __restrict__ ph,
    const unsigned short* __restrict__ pl, float* __restrict__ part)
{
  const int tid  = threadIdx.x;
  const int wave = tid >> 6;
  const int lane = tid & 63;
  const int l15  = lane & 15;
  const int quad = lane >> 4;
  const int ks   = blockIdx.y;
  const int k0   = ks * (D_DIM / NS);
  const int tokw = blockIdx.x * 128 + wave * 32;

  f32x4 acc[2][4];
  #pragma unroll
  for (int s = 0; s < 2; ++s)
    #pragma unroll
    for (int et = 0; et < 4; ++et) acc[s][et] = (f32x4){0.f, 0.f, 0.f, 0.f};

  // x pointers: one per token sub-tile; advance 128 B per chunk.
  const float* xp0 = &x[(size_t)(tokw + l15)      * D_DIM + k0 + quad * 8];
  const float* xp1 = &x[(size_t)(tokw + 16 + l15) * D_DIM + k0 + quad * 8];
  // B pointers: entry (cg*4+quad)*64 + l15 ; et offset = 256 B imm; +4 KB/chunk.
  const unsigned short* bp_h = &ph[(((size_t)(k0 >> 5) * 4 + quad) * 64 + l15) * 8];
  const unsigned short* bp_l = &pl[(((size_t)(k0 >> 5) * 4 + quad) * 64 + l15) * 8];

  // preload chunk 0 x
  float4 a0 = *(const float4*)&xp0[0], a1 = *(const float4*)&xp0[4];
  float4 b0 = *(const float4*)&xp1[0], b1 = *(const float4*)&xp1[4];

  #pragma unroll 1
  for (int c = 0; c < NCH; ++c) {
    // ---- prefetch next chunk's x (stays in flight across the MFMA block) ----
    float4 na0, na1, nb0, nb1;
    if (c + 1 < NCH) {
      const float* q0 = xp0 + (c + 1) * 32;
      const float* q1 = xp1 + (c + 1) * 32;
      na0 = *(const float4*)&q0[0]; na1 = *(const float4*)&q0[4];
      nb0 = *(const float4*)&q1[0]; nb1 = *(const float4*)&q1[4];
    }

    // ---- convert current x to split-bf16 A-frags ----
    bf16x8 ah0, al0, ah1, al1;
    split8(a0, a1, ah0, al0);
    split8(b0, b1, ah1, al1);

    // ---- 4 expert tiles: transient B-frags + 8 MFMAs each ----
    const unsigned short* ch = bp_h + (size_t)c * 2048;   // 4 KB/chunk in shorts
    const unsigned short* cl = bp_l + (size_t)c * 2048;
    #pragma unroll
    for (int et = 0; et < 4; ++et) {
      bf16x8 bh = *(const bf16x8*)&ch[et * 128];
      bf16x8 bl = *(const bf16x8*)&cl[et * 128];
      acc[0][et] = __builtin_amdgcn_mfma_f32_16x16x32_bf16(ah0, bh, acc[0][et], 0, 0, 0);
      acc[0][et] = __builtin_amdgcn_mfma_f32_16x16x32_bf16(ah0, bl, acc[0][et], 0, 0, 0);
      acc[0][et] = __builtin_amdgcn_mfma_f32_16x16x32_bf16(al0, bh, acc[0][et], 0, 0, 0);
      acc[0][et] = __builtin_amdgcn_mfma_f32_16x16x32_bf16(al0, bl, acc[0][et], 0, 0, 0);
      acc[1][et] = __builtin_amdgcn_mfma_f32_16x16x32_bf16(ah1, bh, acc[1][et], 0, 0, 0);
      acc[1][et] = __builtin_amdgcn_mfma_f32_16x16x32_bf16(ah1, bl, acc[1][et], 0, 0, 0);
      acc[1][et] = __builtin_amdgcn_mfma_f32_16x16x32_bf16(al1, bh, acc[1][et], 0, 0, 0);
      acc[1][et] = __builtin_amdgcn_mfma_f32_16x16x32_bf16(al1, bl, acc[1][et], 0, 0, 0);
    }

    a0 = na0; a1 = na1; b0 = nb0; b1 = nb1;
  }

  // ---- store partials: D row = quad*4 + r (token), col = l15 (expert) ----
  #pragma unroll
  for (int sub = 0; sub < 2; ++sub) {
    #pragma unroll
    for (int et = 0; et < 4; ++et) {
      #pragma unroll
      for (int r = 0; r < 4; ++r) {
        const size_t t = (size_t)tokw + sub * 16 + quad * 4 + r;
        part[((size_t)ks * T_TOKENS + t) * E_EXP + et * 16 + l15] = acc[sub][et][r];
      }
    }
  }
}

// ---------------- Kernel 2: reduce + bias, top-8, softmax, counts ----------------
__global__ __launch_bounds__(64) void topk_kernel(
    const float* __restrict__ part, const float* __restrict__ bias,
    float* __restrict__ out)
{
  __shared__ unsigned hist[E_EXP];
  const int tid = threadIdx.x;            // 0..63
  const int t = blockIdx.x * 64 + tid;
  hist[tid] = 0;
  __syncthreads();

  float l[E_EXP];
  #pragma unroll
  for (int j = 0; j < E_EXP / 4; ++j) {
    float4 b = *(const float4*)&bias[j * 4];
    l[4*j] = b.x; l[4*j+1] = b.y; l[4*j+2] = b.z; l[4*j+3] = b.w;
  }
  #pragma unroll 1
  for (int ks = 0; ks < NS; ++ks) {
    const float4* p = (const float4*)&part[((size_t)ks * T_TOKENS + t) * E_EXP];
    #pragma unroll
    for (int j = 0; j < E_EXP / 4; ++j) {
      float4 v = p[j];
      l[4*j] += v.x; l[4*j+1] += v.y; l[4*j+2] += v.z; l[4*j+3] += v.w;
    }
  }

  float tv[TOPK]; int tix[TOPK];
  unsigned long long used = 0ull;
  #pragma unroll
  for (int k = 0; k < TOPK; ++k) {
    float best = -INFINITY; int bi = 0;
    #pragma unroll
    for (int j = 0; j < E_EXP; ++j) {
      bool ok = (((used >> j) & 1ull) == 0ull) && (l[j] > best);  // strict >: lowest index wins ties
      best = ok ? l[j] : best;
      bi   = ok ? j : bi;
    }
    tv[k] = best; tix[k] = bi;
    used |= (1ull << bi);
  }

  float m = tv[0], s = 0.0f, w[TOPK];
  #pragma unroll
  for (int k = 0; k < TOPK; ++k) { w[k] = expf(tv[k] - m); s += w[k]; }
  float inv = 1.0f / s;

  #pragma unroll
  for (int k = 0; k < TOPK; ++k) {
    out[(size_t)t * TOPK + k] = (float)tix[k];                        // indices as fp32
    out[(size_t)T_TOKENS * TOPK + (size_t)t * TOPK + k] = w[k] * inv; // weights
  }

  #pragma unroll
  for (int k = 0; k < TOPK; ++k) atomicAdd(&hist[tix[k]], 1u);
  __syncthreads();
  atomicAdd(&out[2 * (size_t)T_TOKENS * TOPK + tid], (float)hist[tid]);
}

extern "C" void kernel_launch(void* const* d_in, const int* in_sizes, int n_in,
                              void* d_out, int out_size, void* d_ws, size_t ws_size,
                              hipStream_t stream) {
  const float* x    = (const float*)d_in[0];
  const float* gw   = (const float*)d_in[1];
  const float* bias = (const float*)d_in[2];
  float* out  = (float*)d_out;

  // ws layout: part (NS*4 MB) | ph (256 KB) | pl (256 KB)
  float* part = (float*)d_ws;
  const size_t part_elems = (size_t)NS * T_TOKENS * E_EXP;
  unsigned short* ph = (unsigned short*)((char*)d_ws + part_elems * sizeof(float));
  unsigned short* pl = ph + (size_t)E_EXP * D_DIM;

  convert_g_kernel<<<dim3(E_EXP * D_DIM / 8 / 256), dim3(256), 0, stream>>>(
      gw, ph, pl, out + 2 * (size_t)T_TOKENS * TOPK);
  moe_logits_kernel<<<dim3(T_TOKENS / 128, NS), dim3(256), 0, stream>>>(
      x, ph, pl, part);
  topk_kernel<<<dim3(T_TOKENS / 64), dim3(64), 0, stream>>>(part, bias, out);
}